// Round 15
// baseline (205.816 us; speedup 1.0000x reference)
//
#include <hip/hip_runtime.h>
#include <math.h>

typedef unsigned short u16;
typedef short bf16x8 __attribute__((ext_vector_type(8)));
typedef u16 u16x2 __attribute__((ext_vector_type(2)));
typedef u16 u16x4 __attribute__((ext_vector_type(4)));
typedef u16 u16x8 __attribute__((ext_vector_type(8)));
typedef float f32x2 __attribute__((ext_vector_type(2)));
typedef float f32x4 __attribute__((ext_vector_type(4)));
typedef float f32x16 __attribute__((ext_vector_type(16)));

typedef __attribute__((address_space(1))) const void gvoid_t;
typedef __attribute__((address_space(3))) void lvoid_t;

__device__ __forceinline__ u16 f2bf(float f) {
  union { float f; unsigned u; } v; v.f = f;
  unsigned r = v.u + 0x7fffu + ((v.u >> 16) & 1u);
  return (u16)(r >> 16);
}
__device__ __forceinline__ float bf2f(u16 h) {
  union { unsigned u; float f; } v; v.u = ((unsigned)h) << 16;
  return v.f;
}
__device__ __forceinline__ f32x4 mfma16(bf16x8 a, bf16x8 b, f32x4 c) {
  return __builtin_amdgcn_mfma_f32_16x16x32_bf16(a, b, c, 0, 0, 0);
}
__device__ __forceinline__ f32x16 mfma32(bf16x8 a, bf16x8 b, f32x16 c) {
  return __builtin_amdgcn_mfma_f32_32x32x16_bf16(a, b, c, 0, 0, 0);
}
__device__ __forceinline__ void gload_lds16(const void* g, void* l) {
  __builtin_amdgcn_global_load_lds((gvoid_t*)g, (lvoid_t*)l, 16, 0, 0);
}
__device__ __forceinline__ unsigned cvtpk_bf16(float lo, float hi) {
  unsigned r;
  asm("v_cvt_pk_bf16_f32 %0, %1, %2" : "=v"(r) : "v"(lo), "v"(hi));
  return r;
}
__device__ __forceinline__ void pswap32(unsigned& a, unsigned& b) {
  asm("v_permlane32_swap_b32 %0, %1" : "+v"(a), "+v"(b));
}

#if __has_builtin(__builtin_amdgcn_exp2f)
#define EXPW(x) __builtin_amdgcn_exp2f(x)
#define SCALE_W 0.17312354f     /* 0.12 * log2(e) */
#define DEFER_THR 11.5415603f   /* 8 * log2(e) */
#else
#define EXPW(x) __expf(x)
#define SCALE_W 0.12f
#define DEFER_THR 8.0f
#endif

#define BAR() __builtin_amdgcn_s_barrier()
#define WAITLGKM()                          \
  asm volatile("s_waitcnt lgkmcnt(0)");     \
  __builtin_amdgcn_sched_barrier(0)
#define WAITVMC(N)                                    \
  do {                                                \
    __builtin_amdgcn_s_waitcnt(0x0F70 | (N));         \
    __builtin_amdgcn_sched_barrier(0);                \
  } while (0)

// attn class decode: 12 classes per bh, descending extent (LPT).
// st 0..3 whole (extents 4,8,12,16 kv-tiles); st 4..7 split at mid=2st+2
// (extents 10,10,12,12,14,14,16,16).
__constant__ int C_ST2[12] = {7, 7, 3, 6, 6, 5, 5, 2, 4, 4, 1, 0};
__constant__ int C_H2[12]  = {0, 1, -1, 0, 1, 0, 1, -1, 0, 1, -1, -1};

// ---------------- fp32 -> bf16 conversion ----------------
__global__ __launch_bounds__(256) void cvt_bf16_kernel(const float* __restrict__ in,
                                                       u16* __restrict__ out, int n4) {
  int i = blockIdx.x * 256 + threadIdx.x;
  if (i >= n4) return;
  f32x4 v = *(const f32x4*)(in + (size_t)i * 4);
  u16x4 o;
  o[0] = f2bf(v[0]); o[1] = f2bf(v[1]); o[2] = f2bf(v[2]); o[3] = f2bf(v[3]);
  *(u16x4*)(out + (size_t)i * 4) = o;
}

// ---------------- RoPE cos/sin tables [T][64] ----------------
__global__ __launch_bounds__(256) void rope_tab_kernel(float* __restrict__ ct,
                                                       float* __restrict__ st) {
  int i = blockIdx.x * 256 + threadIdx.x;
  int t = i >> 6, j = i & 63;
  float inv = powf(10000.f, -(float)j * (1.0f / 64.0f));
  float ang = (float)t * inv;
  ct[i] = cosf(ang);
  st[i] = sinf(ang);
}

// ---------------- 256x192 2-phase GEMM (R8 version — empirically best) ----------
__global__ __launch_bounds__(512, 1) void gemm192_kernel(
    const u16* __restrict__ A, const u16* __restrict__ B, u16* __restrict__ C,
    int M, int N, int K, int nbn) {
  constexpr int WM = 128;
  constexpr int MI = 4;
  constexpr int NI = 3;
  constexpr int AR = 4;
  constexpr int NR = 7;
  __shared__ u16 Alds[2][256 * 64];
  __shared__ u16 Blds[2][192 * 64];
  int nwg = gridDim.x;
  int cpx = nwg >> 3;
  int bid = blockIdx.x;
  int swz = (bid & 7) * cpx + (bid >> 3);
  int bm = (swz & 3) + 4 * (swz / (4 * nbn));
  int bn = (swz >> 2) % nbn;
  size_t m0 = (size_t)bm * 256, n0 = (size_t)bn * 192;
  int tid = threadIdx.x, wid = tid >> 6, lane = tid & 63;
  int wr = wid >> 2, wc = wid & 3, l15 = lane & 15, l4 = lane >> 4;
  int srow = tid >> 3, sch = tid & 7;

  const u16* Abase = A + m0 * K;
  const u16* Bbase = B + n0 * K;

  f32x4 acc[8][NI];
#pragma unroll
  for (int m = 0; m < 8; m++)
#pragma unroll
    for (int n = 0; n < NI; n++) acc[m][n] = f32x4{0.f, 0.f, 0.f, 0.f};

  auto stageR = [&](int buf, int kt, int r) {
    if (r < AR) {
      int row = 64 * r + srow;
      gload_lds16(Abase + (size_t)row * K + kt * 64 + 8 * (sch ^ (row & 7)),
                  &Alds[buf][(64 * r + 8 * wid) * 64]);
    } else {
      int row = 64 * (r - AR) + srow;
      gload_lds16(Bbase + (size_t)row * K + kt * 64 + 8 * (sch ^ (row & 7)),
                  &Blds[buf][(64 * (r - AR) + 8 * wid) * 64]);
    }
  };
  auto rdA = [&](int buf, int half, bf16x8 (&a)[MI][2]) {
#pragma unroll
    for (int mi = 0; mi < MI; ++mi)
#pragma unroll
      for (int kk = 0; kk < 2; ++kk) {
        int row = WM * wr + 64 * half + 16 * mi + l15;
        a[mi][kk] = *(const bf16x8*)((const char*)(&Alds[buf][0]) + row * 128 +
                                     ((kk * 64 + 16 * l4) ^ ((row & 7) << 4)));
      }
  };
  auto rdB = [&](int buf, bf16x8 (&bb)[NI][2]) {
#pragma unroll
    for (int ni = 0; ni < NI; ++ni)
#pragma unroll
      for (int kk = 0; kk < 2; ++kk) {
        int row = 48 * wc + 16 * ni + l15;
        bb[ni][kk] = *(const bf16x8*)((const char*)(&Blds[buf][0]) + row * 128 +
                                      ((kk * 64 + 16 * l4) ^ ((row & 7) << 4)));
      }
  };

#define HALFM(AF, BF, QM)                                                 \
  do {                                                                    \
    __builtin_amdgcn_s_setprio(1);                                        \
    _Pragma("unroll") for (int mi = 0; mi < MI; ++mi)                     \
        _Pragma("unroll") for (int ni = 0; ni < NI; ++ni)                 \
            _Pragma("unroll") for (int kk = 0; kk < 2; ++kk)              \
                acc[4 * QM + mi][ni] =                                    \
        mfma16(AF[mi][kk], BF[ni][kk], acc[4 * QM + mi][ni]);             \
    __builtin_amdgcn_s_setprio(0);                                        \
  } while (0)

#pragma unroll
  for (int r = 0; r < NR; ++r) stageR(0, 0, r);
  WAITVMC(0);
  BAR();

  int nk = K >> 6;
  bf16x8 a[MI][2], b[NI][2];
  for (int t = 0; t < nk; ++t) {
    int buf = t & 1, nxt = buf ^ 1;
    bool pf = (t + 1 < nk);
    rdA(buf, 0, a);
    rdB(buf, b);
    if (pf) { stageR(nxt, t + 1, 0); stageR(nxt, t + 1, 1); stageR(nxt, t + 1, 2); stageR(nxt, t + 1, 3); }
    BAR();
    WAITLGKM();
    HALFM(a, b, 0);
    BAR();
    rdA(buf, 1, a);
    if (pf) { stageR(nxt, t + 1, 4); stageR(nxt, t + 1, 5); stageR(nxt, t + 1, 6); }
    BAR();
    WAITLGKM();
    HALFM(a, b, 1);
    WAITVMC(0);
    BAR();
  }

#pragma unroll
  for (int mi = 0; mi < 8; ++mi) {
#pragma unroll
    for (int ni = 0; ni < NI; ++ni) {
      size_t row = m0 + WM * wr + 16 * mi + 4 * l4;
      size_t col = n0 + 48 * wc + 16 * ni + l15;
#pragma unroll
      for (int i = 0; i < 4; ++i) {
        C[(row + i) * N + col] = f2bf(acc[mi][ni][i]);
      }
    }
  }
#undef HALFM
}

// ---------------- BM=64 4-phase GEMM (GEMM2) — all staging issued at ph0 ------
template <int BM, int OUTF32>
__global__ __launch_bounds__(512, 1) void gemm4p_kernel(
    const u16* __restrict__ A, const u16* __restrict__ B, void* __restrict__ C,
    const float* __restrict__ bias, int M, int N, int K, int nbn) {
  constexpr int WM = BM / 2;
  constexpr int MI = (WM / 32 > 0) ? WM / 32 : 1;
  constexpr int NACC = 2 * MI;
  constexpr int AR = BM / 64;
  constexpr int NR = AR + 4;
  __shared__ u16 Alds[2][BM * 64];
  __shared__ u16 Blds[2][256 * 64];
  int nwg = gridDim.x;
  int cpx = nwg >> 3;
  int bid = blockIdx.x;
  int swz = (bid & 7) * cpx + (bid >> 3);
  int bm = (swz & 3) + 4 * (swz / (4 * nbn));
  int bn = (swz >> 2) % nbn;
  size_t m0 = (size_t)bm * BM, n0 = (size_t)bn * 256;
  int tid = threadIdx.x, wid = tid >> 6, lane = tid & 63;
  int wr = wid >> 2, wc = wid & 3, l15 = lane & 15, l4 = lane >> 4;
  int srow = tid >> 3, sch = tid & 7;

  const u16* Abase = A + m0 * K;
  const u16* Bbase = B + n0 * K;

  f32x4 acc[NACC][4];
#pragma unroll
  for (int m = 0; m < NACC; m++)
#pragma unroll
    for (int n = 0; n < 4; n++) acc[m][n] = f32x4{0.f, 0.f, 0.f, 0.f};

  auto stageR = [&](int buf, int kt, int r) {
    if (r < AR) {
      int row = 64 * r + srow;
      gload_lds16(Abase + (size_t)row * K + kt * 64 + 8 * (sch ^ (row & 7)),
                  &Alds[buf][(64 * r + 8 * wid) * 64]);
    } else {
      int row = 64 * (r - AR) + srow;
      gload_lds16(Bbase + (size_t)row * K + kt * 64 + 8 * (sch ^ (row & 7)),
                  &Blds[buf][(64 * (r - AR) + 8 * wid) * 64]);
    }
  };
  auto rdA = [&](int buf, int qm, bf16x8 (&a)[MI][2]) {
#pragma unroll
    for (int mi = 0; mi < MI; ++mi)
#pragma unroll
      for (int kk = 0; kk < 2; ++kk) {
        int row = WM * wr + (WM / 2) * qm + 16 * mi + l15;
        a[mi][kk] = *(const bf16x8*)((const char*)(&Alds[buf][0]) + row * 128 +
                                     ((kk * 64 + 16 * l4) ^ ((row & 7) << 4)));
      }
  };
  auto rdB = [&](int buf, int qn, bf16x8 (&bb)[2][2]) {
#pragma unroll
    for (int ni = 0; ni < 2; ++ni)
#pragma unroll
      for (int kk = 0; kk < 2; ++kk) {
        int row = 64 * wc + 32 * qn + 16 * ni + l15;
        bb[ni][kk] = *(const bf16x8*)((const char*)(&Blds[buf][0]) + row * 128 +
                                      ((kk * 64 + 16 * l4) ^ ((row & 7) << 4)));
      }
  };

#define QUADX(AF, BF, QM, QN)                                             \
  do {                                                                    \
    __builtin_amdgcn_s_setprio(1);                                        \
    _Pragma("unroll") for (int mi = 0; mi < MI; ++mi)                     \
        _Pragma("unroll") for (int ni = 0; ni < 2; ++ni)                  \
            _Pragma("unroll") for (int kk = 0; kk < 2; ++kk)              \
                acc[MI * QM + mi][2 * QN + ni] =                          \
        mfma16(AF[mi][kk], BF[ni][kk], acc[MI * QM + mi][2 * QN + ni]);   \
    __builtin_amdgcn_s_setprio(0);                                        \
  } while (0)

#pragma unroll
  for (int r = 0; r < NR; ++r) stageR(0, 0, r);
  WAITVMC(0);
  BAR();

  int nk = K >> 6;
  bf16x8 a[MI][2], b0[2][2], b1[2][2];
  for (int t = 0; t < nk; ++t) {
    int buf = t & 1, nxt = buf ^ 1;
    bool pf = (t + 1 < nk);
    rdA(buf, 0, a);
    rdB(buf, 0, b0);
    if (pf) {
#pragma unroll
      for (int r = 0; r < NR; ++r) stageR(nxt, t + 1, r);
    }
    BAR();
    WAITLGKM();
    QUADX(a, b0, 0, 0);
    BAR();
    rdB(buf, 1, b1);
    BAR();
    WAITLGKM();
    QUADX(a, b1, 0, 1);
    BAR();
    rdA(buf, 1, a);
    BAR();
    WAITLGKM();
    QUADX(a, b0, 1, 0);
    BAR();
    QUADX(a, b1, 1, 1);
    WAITVMC(0);
    BAR();
  }

#pragma unroll
  for (int mi = 0; mi < NACC; ++mi) {
#pragma unroll
    for (int ni = 0; ni < 4; ++ni) {
      size_t row = m0 + WM * wr + 16 * mi + 4 * l4;
      size_t col = n0 + 64 * wc + 16 * ni + l15;
#pragma unroll
      for (int i = 0; i < 4; ++i) {
        float v = acc[mi][ni][i];
        if constexpr (OUTF32) {
          ((float*)C)[(row + i) * N + col] = v + bias[col];
        } else {
          ((u16*)C)[(row + i) * N + col] = f2bf(v);
        }
      }
    }
  }
#undef QUADX
}

// ---------------- transform: RMSNorm + RoPE + v-mix ----------------
__global__ __launch_bounds__(256) void transform_kernel(
    const u16* __restrict__ qkv, const float* __restrict__ ve,
    const float* __restrict__ lam, const float* __restrict__ ct,
    const float* __restrict__ st, u16* __restrict__ qn, u16* __restrict__ kn,
    u16* __restrict__ vt) {
  constexpr int T = 2048;
  __shared__ u16 vtile[64][136];
  int tt = blockIdx.x, bh = blockIdx.y;
  int b = bh >> 3, h = bh & 7;
  int tid = threadIdx.x, wid = tid >> 6, lane = tid & 63;
  int lsub = lane & 15, lrow = lane >> 4;
  float l0 = lam[0], l1 = lam[1];
  int d0 = 8 * lsub;
  float sgn = (lsub < 8) ? -1.f : 1.f;
  int jj = d0 & 63;
#pragma unroll
  for (int it = 0; it < 4; ++it) {
    int tl = wid * 16 + it * 4 + lrow;
    int t = tt * 64 + tl;
    size_t base = ((size_t)(b * T + t)) * 3072 + h * 128 + d0;
    u16x8 qraw = *(const u16x8*)(qkv + base);
    u16x8 kraw = *(const u16x8*)(qkv + base + 1024);
    u16x8 vraw = *(const u16x8*)(qkv + base + 2048);
    const float* vep = ve + ((size_t)(b * T + t)) * 1024 + h * 128 + d0;
    f32x4 ve0 = *(const f32x4*)(vep);
    f32x4 ve1 = *(const f32x4*)(vep + 4);
    float q[8], k[8];
    float sq = 0.f, sk = 0.f;
#pragma unroll
    for (int i = 0; i < 8; ++i) {
      q[i] = bf2f(qraw[i]); k[i] = bf2f(kraw[i]);
      sq += q[i] * q[i]; sk += k[i] * k[i];
    }
#pragma unroll
    for (int m = 1; m < 16; m <<= 1) {
      sq += __shfl_xor(sq, m);
      sk += __shfl_xor(sk, m);
    }
    float qs = rsqrtf(sq * (1.f / 128.f) + 1.1920929e-7f);
    float ks = rsqrtf(sk * (1.f / 128.f) + 1.1920929e-7f);
#pragma unroll
    for (int i = 0; i < 8; ++i) { q[i] *= qs; k[i] *= ks; }
    f32x4 c0 = *(const f32x4*)(ct + t * 64 + jj);
    f32x4 c1 = *(const f32x4*)(ct + t * 64 + jj + 4);
    f32x4 s0 = *(const f32x4*)(st + t * 64 + jj);
    f32x4 s1 = *(const f32x4*)(st + t * 64 + jj + 4);
    u16x8 oq, ok, ov;
#pragma unroll
    for (int i = 0; i < 8; ++i) {
      float qp = __shfl_xor(q[i], 8), kp = __shfl_xor(k[i], 8);
      float cc = (i < 4) ? c0[i & 3] : c1[i & 3];
      float ss = (i < 4) ? s0[i & 3] : s1[i & 3];
      oq[i] = f2bf(q[i] * cc + sgn * qp * ss);
      ok[i] = f2bf(k[i] * cc + sgn * kp * ss);
      float vv = (i < 4) ? ve0[i & 3] : ve1[i & 3];
      ov[i] = f2bf(l0 * bf2f(vraw[i]) + l1 * vv);
    }
    size_t orow = ((size_t)bh * T + t) * 128 + d0;
    *(u16x8*)(qn + orow) = oq;
    *(u16x8*)(kn + orow) = ok;
    *(u16x8*)&vtile[tl][d0] = ov;
  }
  __syncthreads();
#pragma unroll
  for (int it = 0; it < 4; ++it) {
    int ci = it * 256 + tid;
    int d = ci >> 3, c8 = ci & 7;
    u16x8 o;
#pragma unroll
    for (int u = 0; u < 8; u++) o[u] = vtile[c8 * 8 + u][d];
    *(u16x8*)(vt + ((size_t)bh * 128 + d) * T + tt * 64 + c8 * 8) = o;
  }
}

// ---------------- causal flash attention: 8-wave 256q blocks + kv-split (LPT) ----------
// 384 blocks = 12 classes x 32 bh, class-major descending extent. st<4 whole -> Y;
// st>=4 split at mid=2st+2 -> unnormalized partials (bf16 acc + f32 m,l), merged below.
__global__ __launch_bounds__(512, 2) void attn_kernel(
    const u16* __restrict__ Qn, const u16* __restrict__ Kn,
    const u16* __restrict__ Vt, u16* __restrict__ Y,
    u16* __restrict__ pO, float* __restrict__ pml) {
  constexpr int T = 2048;
  __shared__ u16 Klds[2][64 * 128];
  __shared__ u16 Vlds[2][128 * 64];
  int bid = blockIdx.x;
  int c = bid >> 5;
  int bh = bid & 31;
  int st = C_ST2[c];
  int hf = C_H2[c];
  int mid = 2 * st + 2;
  int kt0 = (hf == 1) ? mid : 0;
  int kt1 = (hf == 0) ? mid : 4 * st + 4;
  int b = bh >> 3, h = bh & 7;
  int tid = threadIdx.x, wid = tid >> 6, lane = tid & 63;
  int l31 = lane & 31, hh = lane >> 5;
  const u16* Qb = Qn + (size_t)bh * T * 128;
  const u16* Kb = Kn + (size_t)bh * T * 128;
  const u16* Vb = Vt + (size_t)bh * 128 * T;
  int q0w = st * 256 + wid * 32;    // 8 waves x 32 rows = 256
  int qmaxw = q0w + 31;
  int qg = q0w + l31;

  bf16x8 qf[8];
  {
    const u16* qr = Qb + (size_t)(q0w + l31) * 128 + 8 * hh;
#pragma unroll
    for (int ks = 0; ks < 8; ks++) qf[ks] = *(const bf16x8*)(qr + 16 * ks);
  }
  f32x16 acc[4];
#pragma unroll
  for (int mt = 0; mt < 4; mt++)
#pragma unroll
    for (int r = 0; r < 16; r++) acc[mt][r] = 0.f;
  float m_run = -1e30f, l_run = 0.f;

  // 512 threads stage K(64x128) + V(128x64): 4 gloads/thread
  auto stage = [&](int buf, int kt) {
#pragma unroll
    for (int it = 0; it < 2; ++it) {
      int id = it * 512 + tid;            // 0..1023
      int r = id >> 4, cc = id & 15;
      gload_lds16(Kb + (size_t)(kt * 64 + r) * 128 + 8 * (cc ^ (r & 7)),
                  &Klds[buf][(size_t)(it * 512 + (tid & ~63)) * 8]);
      int rv = id >> 3, cv = id & 7;
      gload_lds16(Vb + (size_t)rv * T + kt * 64 + 8 * (cv ^ (rv & 7)),
                  &Vlds[buf][(size_t)(it * 512 + (tid & ~63)) * 8]);
    }
  };

  int nsteps = kt1 - kt0;
  stage(0, kt0);

  for (int j = 0; j < nsteps; ++j) {
    int kt = kt0 + j;
    int cur = j & 1;
    if (j + 1 < nsteps) {
      stage(cur ^ 1, kt + 1);
      WAITVMC(4);          // current tile landed; next tile's 4 stay in flight
    } else {
      WAITVMC(0);
    }
    BAR();
    if (kt * 64 <= qmaxw) {
      const char* kb = (const char*)&Klds[cur][0];
      const char* vb = (const char*)&Vlds[cur][0];
      int rswz = (l31 & 7) << 4;
      f32x16 st0, st1;
#pragma unroll
      for (int r = 0; r < 16; r++) { st0[r] = 0.f; st1[r] = 0.f; }
      __builtin_amdgcn_s_setprio(1);
#pragma unroll
      for (int ks = 0; ks < 8; ks++) {
        bf16x8 kf0 = *(const bf16x8*)(kb + ((l31 * 256 + 32 * ks + 16 * hh) ^ rswz));
        bf16x8 kf1 = *(const bf16x8*)(kb + (((32 + l31) * 256 + 32 * ks + 16 * hh) ^ rswz));
        st0 = mfma32(kf0, qf[ks], st0);
        st1 = mfma32(kf1, qf[ks], st1);
      }
      __builtin_amdgcn_s_setprio(0);
      bool edge = (kt == (qmaxw >> 6));
      if (edge) {
#pragma unroll
        for (int r = 0; r < 16; r++) {
          int kvb = kt * 64 + (r & 3) + 8 * (r >> 2) + 4 * hh;
          if (kvb > qg) st0[r] = -1e30f;
          if (kvb + 32 > qg) st1[r] = -1e30f;
        }
      }
      float m8[8];
#pragma unroll
      for (int r = 0; r < 8; r++)
        m8[r] = fmaxf(fmaxf(st0[r], st0[r + 8]), fmaxf(st1[r], st1[r + 8]));
#pragma unroll
      for (int r = 0; r < 4; r++) m8[r] = fmaxf(m8[r], m8[r + 4]);
      float pm = fmaxf(fmaxf(m8[0], m8[1]), fmaxf(m8[2], m8[3]));
      pm = fmaxf(pm, __shfl_xor(pm, 32));
      float pmn = pm * SCALE_W;
      bool nos = __all(pmn <= m_run + DEFER_THR);
      float mnew = nos ? m_run : fmaxf(m_run, pmn);
      if (!nos) {
        float alpha = EXPW(m_run - mnew);
        l_run *= alpha;
#pragma unroll
        for (int mt = 0; mt < 4; mt++)
#pragma unroll
          for (int r = 0; r < 16; r++) acc[mt][r] *= alpha;
        m_run = mnew;
      }
      float sa = 0.f, sb = 0.f, sc = 0.f, sd = 0.f;
#pragma unroll
      for (int r = 0; r < 4; r++) {
        st0[r]      = EXPW(fmaf(st0[r],      SCALE_W, -mnew)); sa += st0[r];
        st0[r + 4]  = EXPW(fmaf(st0[r + 4],  SCALE_W, -mnew)); sb += st0[r + 4];
        st0[r + 8]  = EXPW(fmaf(st0[r + 8],  SCALE_W, -mnew)); sc += st0[r + 8];
        st0[r + 12] = EXPW(fmaf(st0[r + 12], SCALE_W, -mnew)); sd += st0[r + 12];
        st1[r]      = EXPW(fmaf(st1[r],      SCALE_W, -mnew)); sa += st1[r];
        st1[r + 4]  = EXPW(fmaf(st1[r + 4],  SCALE_W, -mnew)); sb += st1[r + 4];
        st1[r + 8]  = EXPW(fmaf(st1[r + 8],  SCALE_W, -mnew)); sc += st1[r + 8];
        st1[r + 12] = EXPW(fmaf(st1[r + 12], SCALE_W, -mnew)); sd += st1[r + 12];
      }
      float ps = (sa + sb) + (sc + sd);
      ps += __shfl_xor(ps, 32);
      l_run += ps;
      unsigned pA0[4], pB0[4], pA1[4], pB1[4];
#pragma unroll
      for (int rr = 0; rr < 4; rr++) {
        pA0[rr] = cvtpk_bf16(st0[4 * rr], st0[4 * rr + 1]);
        pB0[rr] = cvtpk_bf16(st0[4 * rr + 2], st0[4 * rr + 3]);
        pA1[rr] = cvtpk_bf16(st1[4 * rr], st1[4 * rr + 1]);
        pB1[rr] = cvtpk_bf16(st1[4 * rr + 2], st1[4 * rr + 3]);
      }
      bf16x8 pf[4];
#pragma unroll
      for (int ks2 = 0; ks2 < 4; ks2++) {
        int k1 = ks2 & 1;
        unsigned a0, b0, a1, b1;
        if (ks2 < 2) { a0 = pA0[2 * k1]; b0 = pA0[2 * k1 + 1]; a1 = pB0[2 * k1]; b1 = pB0[2 * k1 + 1]; }
        else         { a0 = pA1[2 * k1]; b0 = pA1[2 * k1 + 1]; a1 = pB1[2 * k1]; b1 = pB1[2 * k1 + 1]; }
        pswap32(a0, b0);
        pswap32(a1, b1);
        union { unsigned w[4]; bf16x8 v; } u;
        u.w[0] = a0; u.w[1] = a1; u.w[2] = b0; u.w[3] = b1;
        pf[ks2] = u.v;
      }
      __builtin_amdgcn_s_setprio(1);
#pragma unroll
      for (int mt = 0; mt < 4; mt++) {
        int row = 32 * mt + l31;
#pragma unroll
        for (int ks2 = 0; ks2 < 4; ks2++) {
          bf16x8 vf = *(const bf16x8*)(vb + ((row * 128 + 32 * ks2 + 16 * hh) ^ rswz));
          acc[mt] = mfma32(vf, pf[ks2], acc[mt]);
        }
      }
      __builtin_amdgcn_s_setprio(0);
    }
    BAR();
  }
  if (hf < 0) {
    float linv = 1.f / l_run;
    size_t yrow = (size_t)b * T + q0w + l31;
    u16* yp = Y + yrow * 1024 + h * 128;
#pragma unroll
    for (int mt = 0; mt < 4; mt++) {
#pragma unroll
      for (int rr = 0; rr < 4; rr++) {
        u16x4 o;
#pragma unroll
        for (int i = 0; i < 4; i++) o[i] = f2bf(acc[mt][4 * rr + i] * linv);
        *(u16x4*)(yp + 32 * mt + 8 * rr + 4 * hh) = o;
      }
    }
  } else {
    int sidx = st - 4;
    int pidx = (sidx * 32 + bh) * 2 + hf;
    int qrow = wid * 32 + l31;
    u16* po = pO + (size_t)pidx * 32768 + (size_t)qrow * 128;
#pragma unroll
    for (int mt = 0; mt < 4; mt++) {
#pragma unroll
      for (int rr = 0; rr < 4; rr++) {
        u16x4 o;
#pragma unroll
        for (int i = 0; i < 4; i++) o[i] = f2bf(acc[mt][4 * rr + i]);
        *(u16x4*)(po + 32 * mt + 8 * rr + 4 * hh) = o;
      }
    }
    if (hh == 0) {
      pml[pidx * 512 + qrow] = m_run;
      pml[pidx * 512 + 256 + qrow] = l_run;
    }
  }
}

// ---------------- merge two kv-half partials -> Y ----------------
__global__ __launch_bounds__(256) void attn_merge_kernel(
    const u16* __restrict__ pO, const float* __restrict__ pml,
    u16* __restrict__ Y) {
  int blk = blockIdx.x;             // 256 blocks: task = blk>>1, rowhalf = blk&1
  int task = blk >> 1, rh = blk & 1;
  int st = 4 + (task >> 5), bh = task & 31;
  int b = bh >> 3, h = bh & 7;
  int tid = threadIdx.x;
  int row = rh * 128 + (tid >> 1), dh = tid & 1;
  int base = task * 2;
  const u16* o1 = pO + (size_t)base * 32768 + (size_t)row * 128 + dh * 64;
  const u16* o2 = o1 + 32768;
  float m1 = pml[base * 512 + row], l1 = pml[base * 512 + 256 + row];
  float m2 = pml[(base + 1) * 512 + row], l2 = pml[(base + 1) * 512 + 256 + row];
  float m = fmaxf(m1, m2);
  float w1 = EXPW(m1 - m), w2 = EXPW(m2 - m);
  float inv = 1.f / (w1 * l1 + w2 * l2);
  w1 *= inv; w2 *= inv;
  u16* yp = Y + ((size_t)b * 2048 + 256 * st + row) * 1024 + h * 128 + dh * 64;
#pragma unroll
  for (int i = 0; i < 8; ++i) {
    u16x8 a = *(const u16x8*)(o1 + 8 * i);
    u16x8 cvec = *(const u16x8*)(o2 + 8 * i);
    u16x8 o;
#pragma unroll
    for (int j = 0; j < 8; ++j) o[j] = f2bf(w1 * bf2f(a[j]) + w2 * bf2f(cvec[j]));
    *(u16x8*)(yp + 8 * i) = o;
  }
}

// ---------------- launch ----------------
extern "C" void kernel_launch(void* const* d_in, const int* in_sizes, int n_in,
                              void* d_out, int out_size, void* d_ws, size_t ws_size,
                              hipStream_t stream) {
  (void)in_sizes; (void)n_in; (void)out_size; (void)ws_size;
  const float* x = (const float*)d_in[0];
  const float* ve = (const float*)d_in[1];
  const float* qkvw = (const float*)d_in[2];
  const float* lam = (const float*)d_in[3];
  const float* cpw = (const float*)d_in[4];
  const float* cpb = (const float*)d_in[5];
  float* out = (float*)d_out;
  char* ws = (char*)d_ws;

  u16* xb   = (u16*)(ws + 0);           // 16 MB  (aliased by y after GEMM1)
  u16* wqkv = (u16*)(ws + 16777216);    // 6 MB
  u16* wp   = (u16*)(ws + 23068672);    // 2 MB
  u16* qkv  = (u16*)(ws + 25165824);    // 48 MB (partials alias after transform)
  u16* qn   = (u16*)(ws + 75497472);    // 16 MB
  u16* kn   = (u16*)(ws + 92274688);    // 16 MB
  u16* vt   = (u16*)(ws + 109051904);   // 16 MB
  float* ctab = (float*)(ws + 125829120);  // 0.5 MB
  float* stab = (float*)(ws + 126353408);  // 0.5 MB
  u16* y = xb;                          // alias: xb dead after GEMM1
  u16* pO = qkv;                        // alias: qkv dead after transform (16 MB used)
  float* pml = (float*)(ws + 25165824 + 16777216);  // 0.5 MB

  rope_tab_kernel<<<512, 256, 0, stream>>>(ctab, stab);
  cvt_bf16_kernel<<<8192, 256, 0, stream>>>(x, xb, 2097152);
  cvt_bf16_kernel<<<3072, 256, 0, stream>>>(qkvw, wqkv, 786432);
  cvt_bf16_kernel<<<1024, 256, 0, stream>>>(cpw, wp, 262144);
  gemm192_kernel<<<512, 512, 0, stream>>>(xb, wqkv, qkv, 8192, 3072, 1024, 16);
  transform_kernel<<<dim3(32, 32), 256, 0, stream>>>(qkv, ve, lam, ctab, stab, qn, kn, vt);
  attn_kernel<<<384, 512, 0, stream>>>(qn, kn, vt, y, pO, pml);
  attn_merge_kernel<<<256, 256, 0, stream>>>(pO, pml, y);
  gemm4p_kernel<64, 1><<<512, 512, 0, stream>>>(y, wp, out, cpb, 8192, 1024, 1024, 4);
}

// Round 16
// 185.616 us; speedup vs baseline: 1.1088x; 1.1088x over previous
//
#include <hip/hip_runtime.h>
#include <math.h>

typedef unsigned short u16;
typedef short bf16x8 __attribute__((ext_vector_type(8)));
typedef u16 u16x2 __attribute__((ext_vector_type(2)));
typedef u16 u16x4 __attribute__((ext_vector_type(4)));
typedef u16 u16x8 __attribute__((ext_vector_type(8)));
typedef float f32x2 __attribute__((ext_vector_type(2)));
typedef float f32x4 __attribute__((ext_vector_type(4)));
typedef float f32x16 __attribute__((ext_vector_type(16)));

typedef __attribute__((address_space(1))) const void gvoid_t;
typedef __attribute__((address_space(3))) void lvoid_t;

__device__ __forceinline__ u16 f2bf(float f) {
  union { float f; unsigned u; } v; v.f = f;
  unsigned r = v.u + 0x7fffu + ((v.u >> 16) & 1u);
  return (u16)(r >> 16);
}
__device__ __forceinline__ float bf2f(u16 h) {
  union { unsigned u; float f; } v; v.u = ((unsigned)h) << 16;
  return v.f;
}
__device__ __forceinline__ f32x4 mfma16(bf16x8 a, bf16x8 b, f32x4 c) {
  return __builtin_amdgcn_mfma_f32_16x16x32_bf16(a, b, c, 0, 0, 0);
}
__device__ __forceinline__ f32x16 mfma32(bf16x8 a, bf16x8 b, f32x16 c) {
  return __builtin_amdgcn_mfma_f32_32x32x16_bf16(a, b, c, 0, 0, 0);
}
__device__ __forceinline__ void gload_lds16(const void* g, void* l) {
  __builtin_amdgcn_global_load_lds((gvoid_t*)g, (lvoid_t*)l, 16, 0, 0);
}
__device__ __forceinline__ unsigned cvtpk_bf16(float lo, float hi) {
  unsigned r;
  asm("v_cvt_pk_bf16_f32 %0, %1, %2" : "=v"(r) : "v"(lo), "v"(hi));
  return r;
}
__device__ __forceinline__ void pswap32(unsigned& a, unsigned& b) {
  asm("v_permlane32_swap_b32 %0, %1" : "+v"(a), "+v"(b));
}

#if __has_builtin(__builtin_amdgcn_exp2f)
#define EXPW(x) __builtin_amdgcn_exp2f(x)
#define SCALE_W 0.17312354f     /* 0.12 * log2(e) */
#define DEFER_THR 11.5415603f   /* 8 * log2(e) */
#else
#define EXPW(x) __expf(x)
#define SCALE_W 0.12f
#define DEFER_THR 8.0f
#endif

#define BAR() __builtin_amdgcn_s_barrier()
#define WAITLGKM()                          \
  asm volatile("s_waitcnt lgkmcnt(0)");     \
  __builtin_amdgcn_sched_barrier(0)
#define WAITVMC(N)                                    \
  do {                                                \
    __builtin_amdgcn_s_waitcnt(0x0F70 | (N));         \
    __builtin_amdgcn_sched_barrier(0);                \
  } while (0)

// ---------------- fused init: fp32->bf16 for x/qkvw/cpw + RoPE tables ----------------
// blocks [0,8192): x (2097152 f32x4); [8192,11264): qkvw (786432); [11264,12288): cpw
// (262144); [12288,12800): rope tables (131072 scalars). All ranges block-uniform.
__global__ __launch_bounds__(256) void init_kernel(
    const float* __restrict__ x, const float* __restrict__ qkvw,
    const float* __restrict__ cpw, u16* __restrict__ xb, u16* __restrict__ wqkv,
    u16* __restrict__ wp, float* __restrict__ ct, float* __restrict__ st) {
  int blk = blockIdx.x;
  if (blk < 12288) {
    int i = blk * 256 + threadIdx.x;
    const float* src;
    u16* dst;
    int off;
    if (i < 2097152) { src = x; dst = xb; off = i; }
    else if (i < 2883584) { src = qkvw; dst = wqkv; off = i - 2097152; }
    else { src = cpw; dst = wp; off = i - 2883584; }
    f32x4 v = *(const f32x4*)(src + (size_t)off * 4);
    u16x4 o;
    o[0] = f2bf(v[0]); o[1] = f2bf(v[1]); o[2] = f2bf(v[2]); o[3] = f2bf(v[3]);
    *(u16x4*)(dst + (size_t)off * 4) = o;
  } else {
    int i = (blk - 12288) * 256 + threadIdx.x;   // 0..131071
    int t = i >> 6, j = i & 63;
    float inv = powf(10000.f, -(float)j * (1.0f / 64.0f));
    float ang = (float)t * inv;
    ct[i] = cosf(ang);
    st[i] = sinf(ang);
  }
}

// ---------------- 256x192 2-phase GEMM (empirically best; GEMM1) ----------
__global__ __launch_bounds__(512, 1) void gemm192_kernel(
    const u16* __restrict__ A, const u16* __restrict__ B, u16* __restrict__ C,
    int M, int N, int K, int nbn) {
  constexpr int WM = 128;
  constexpr int MI = 4;
  constexpr int NI = 3;
  constexpr int AR = 4;
  constexpr int NR = 7;
  __shared__ u16 Alds[2][256 * 64];
  __shared__ u16 Blds[2][192 * 64];
  int nwg = gridDim.x;
  int cpx = nwg >> 3;
  int bid = blockIdx.x;
  int swz = (bid & 7) * cpx + (bid >> 3);
  int bm = (swz & 3) + 4 * (swz / (4 * nbn));
  int bn = (swz >> 2) % nbn;
  size_t m0 = (size_t)bm * 256, n0 = (size_t)bn * 192;
  int tid = threadIdx.x, wid = tid >> 6, lane = tid & 63;
  int wr = wid >> 2, wc = wid & 3, l15 = lane & 15, l4 = lane >> 4;
  int srow = tid >> 3, sch = tid & 7;

  const u16* Abase = A + m0 * K;
  const u16* Bbase = B + n0 * K;

  f32x4 acc[8][NI];
#pragma unroll
  for (int m = 0; m < 8; m++)
#pragma unroll
    for (int n = 0; n < NI; n++) acc[m][n] = f32x4{0.f, 0.f, 0.f, 0.f};

  auto stageR = [&](int buf, int kt, int r) {
    if (r < AR) {
      int row = 64 * r + srow;
      gload_lds16(Abase + (size_t)row * K + kt * 64 + 8 * (sch ^ (row & 7)),
                  &Alds[buf][(64 * r + 8 * wid) * 64]);
    } else {
      int row = 64 * (r - AR) + srow;
      gload_lds16(Bbase + (size_t)row * K + kt * 64 + 8 * (sch ^ (row & 7)),
                  &Blds[buf][(64 * (r - AR) + 8 * wid) * 64]);
    }
  };
  auto rdA = [&](int buf, int half, bf16x8 (&a)[MI][2]) {
#pragma unroll
    for (int mi = 0; mi < MI; ++mi)
#pragma unroll
      for (int kk = 0; kk < 2; ++kk) {
        int row = WM * wr + 64 * half + 16 * mi + l15;
        a[mi][kk] = *(const bf16x8*)((const char*)(&Alds[buf][0]) + row * 128 +
                                     ((kk * 64 + 16 * l4) ^ ((row & 7) << 4)));
      }
  };
  auto rdB = [&](int buf, bf16x8 (&bb)[NI][2]) {
#pragma unroll
    for (int ni = 0; ni < NI; ++ni)
#pragma unroll
      for (int kk = 0; kk < 2; ++kk) {
        int row = 48 * wc + 16 * ni + l15;
        bb[ni][kk] = *(const bf16x8*)((const char*)(&Blds[buf][0]) + row * 128 +
                                      ((kk * 64 + 16 * l4) ^ ((row & 7) << 4)));
      }
  };

#define HALFM(AF, BF, QM)                                                 \
  do {                                                                    \
    __builtin_amdgcn_s_setprio(1);                                        \
    _Pragma("unroll") for (int mi = 0; mi < MI; ++mi)                     \
        _Pragma("unroll") for (int ni = 0; ni < NI; ++ni)                 \
            _Pragma("unroll") for (int kk = 0; kk < 2; ++kk)              \
                acc[4 * QM + mi][ni] =                                    \
        mfma16(AF[mi][kk], BF[ni][kk], acc[4 * QM + mi][ni]);             \
    __builtin_amdgcn_s_setprio(0);                                        \
  } while (0)

#pragma unroll
  for (int r = 0; r < NR; ++r) stageR(0, 0, r);
  WAITVMC(0);
  BAR();

  int nk = K >> 6;
  bf16x8 a[MI][2], b[NI][2];
  for (int t = 0; t < nk; ++t) {
    int buf = t & 1, nxt = buf ^ 1;
    bool pf = (t + 1 < nk);
    rdA(buf, 0, a);
    rdB(buf, b);
    if (pf) { stageR(nxt, t + 1, 0); stageR(nxt, t + 1, 1); stageR(nxt, t + 1, 2); stageR(nxt, t + 1, 3); }
    BAR();
    WAITLGKM();
    HALFM(a, b, 0);
    BAR();
    rdA(buf, 1, a);
    if (pf) { stageR(nxt, t + 1, 4); stageR(nxt, t + 1, 5); stageR(nxt, t + 1, 6); }
    BAR();
    WAITLGKM();
    HALFM(a, b, 1);
    WAITVMC(0);
    BAR();
  }

#pragma unroll
  for (int mi = 0; mi < 8; ++mi) {
#pragma unroll
    for (int ni = 0; ni < NI; ++ni) {
      size_t row = m0 + WM * wr + 16 * mi + 4 * l4;
      size_t col = n0 + 48 * wc + 16 * ni + l15;
#pragma unroll
      for (int i = 0; i < 4; ++i) {
        C[(row + i) * N + col] = f2bf(acc[mi][ni][i]);
      }
    }
  }
#undef HALFM
}

// ---------------- BM=64 4-phase GEMM (GEMM2) — all staging issued at ph0 ------
template <int BM, int OUTF32>
__global__ __launch_bounds__(512, 1) void gemm4p_kernel(
    const u16* __restrict__ A, const u16* __restrict__ B, void* __restrict__ C,
    const float* __restrict__ bias, int M, int N, int K, int nbn) {
  constexpr int WM = BM / 2;
  constexpr int MI = (WM / 32 > 0) ? WM / 32 : 1;
  constexpr int NACC = 2 * MI;
  constexpr int AR = BM / 64;
  constexpr int NR = AR + 4;
  __shared__ u16 Alds[2][BM * 64];
  __shared__ u16 Blds[2][256 * 64];
  int nwg = gridDim.x;
  int cpx = nwg >> 3;
  int bid = blockIdx.x;
  int swz = (bid & 7) * cpx + (bid >> 3);
  int bm = (swz & 3) + 4 * (swz / (4 * nbn));
  int bn = (swz >> 2) % nbn;
  size_t m0 = (size_t)bm * BM, n0 = (size_t)bn * 256;
  int tid = threadIdx.x, wid = tid >> 6, lane = tid & 63;
  int wr = wid >> 2, wc = wid & 3, l15 = lane & 15, l4 = lane >> 4;
  int srow = tid >> 3, sch = tid & 7;

  const u16* Abase = A + m0 * K;
  const u16* Bbase = B + n0 * K;

  f32x4 acc[NACC][4];
#pragma unroll
  for (int m = 0; m < NACC; m++)
#pragma unroll
    for (int n = 0; n < 4; n++) acc[m][n] = f32x4{0.f, 0.f, 0.f, 0.f};

  auto stageR = [&](int buf, int kt, int r) {
    if (r < AR) {
      int row = 64 * r + srow;
      gload_lds16(Abase + (size_t)row * K + kt * 64 + 8 * (sch ^ (row & 7)),
                  &Alds[buf][(64 * r + 8 * wid) * 64]);
    } else {
      int row = 64 * (r - AR) + srow;
      gload_lds16(Bbase + (size_t)row * K + kt * 64 + 8 * (sch ^ (row & 7)),
                  &Blds[buf][(64 * (r - AR) + 8 * wid) * 64]);
    }
  };
  auto rdA = [&](int buf, int qm, bf16x8 (&a)[MI][2]) {
#pragma unroll
    for (int mi = 0; mi < MI; ++mi)
#pragma unroll
      for (int kk = 0; kk < 2; ++kk) {
        int row = WM * wr + (WM / 2) * qm + 16 * mi + l15;
        a[mi][kk] = *(const bf16x8*)((const char*)(&Alds[buf][0]) + row * 128 +
                                     ((kk * 64 + 16 * l4) ^ ((row & 7) << 4)));
      }
  };
  auto rdB = [&](int buf, int qn, bf16x8 (&bb)[2][2]) {
#pragma unroll
    for (int ni = 0; ni < 2; ++ni)
#pragma unroll
      for (int kk = 0; kk < 2; ++kk) {
        int row = 64 * wc + 32 * qn + 16 * ni + l15;
        bb[ni][kk] = *(const bf16x8*)((const char*)(&Blds[buf][0]) + row * 128 +
                                      ((kk * 64 + 16 * l4) ^ ((row & 7) << 4)));
      }
  };

#define QUADX(AF, BF, QM, QN)                                             \
  do {                                                                    \
    __builtin_amdgcn_s_setprio(1);                                        \
    _Pragma("unroll") for (int mi = 0; mi < MI; ++mi)                     \
        _Pragma("unroll") for (int ni = 0; ni < 2; ++ni)                  \
            _Pragma("unroll") for (int kk = 0; kk < 2; ++kk)              \
                acc[MI * QM + mi][2 * QN + ni] =                          \
        mfma16(AF[mi][kk], BF[ni][kk], acc[MI * QM + mi][2 * QN + ni]);   \
    __builtin_amdgcn_s_setprio(0);                                        \
  } while (0)

#pragma unroll
  for (int r = 0; r < NR; ++r) stageR(0, 0, r);
  WAITVMC(0);
  BAR();

  int nk = K >> 6;
  bf16x8 a[MI][2], b0[2][2], b1[2][2];
  for (int t = 0; t < nk; ++t) {
    int buf = t & 1, nxt = buf ^ 1;
    bool pf = (t + 1 < nk);
    rdA(buf, 0, a);
    rdB(buf, 0, b0);
    if (pf) {
#pragma unroll
      for (int r = 0; r < NR; ++r) stageR(nxt, t + 1, r);
    }
    BAR();
    WAITLGKM();
    QUADX(a, b0, 0, 0);
    BAR();
    rdB(buf, 1, b1);
    BAR();
    WAITLGKM();
    QUADX(a, b1, 0, 1);
    BAR();
    rdA(buf, 1, a);
    BAR();
    WAITLGKM();
    QUADX(a, b0, 1, 0);
    BAR();
    QUADX(a, b1, 1, 1);
    WAITVMC(0);
    BAR();
  }

#pragma unroll
  for (int mi = 0; mi < NACC; ++mi) {
#pragma unroll
    for (int ni = 0; ni < 4; ++ni) {
      size_t row = m0 + WM * wr + 16 * mi + 4 * l4;
      size_t col = n0 + 64 * wc + 16 * ni + l15;
#pragma unroll
      for (int i = 0; i < 4; ++i) {
        float v = acc[mi][ni][i];
        if constexpr (OUTF32) {
          ((float*)C)[(row + i) * N + col] = v + bias[col];
        } else {
          ((u16*)C)[(row + i) * N + col] = f2bf(v);
        }
      }
    }
  }
#undef QUADX
}

// ---------------- transform: RMSNorm + RoPE + v-mix ----------------
__global__ __launch_bounds__(256) void transform_kernel(
    const u16* __restrict__ qkv, const float* __restrict__ ve,
    const float* __restrict__ lam, const float* __restrict__ ct,
    const float* __restrict__ st, u16* __restrict__ qn, u16* __restrict__ kn,
    u16* __restrict__ vt) {
  constexpr int T = 2048;
  __shared__ u16 vtile[64][136];
  int tt = blockIdx.x, bh = blockIdx.y;
  int b = bh >> 3, h = bh & 7;
  int tid = threadIdx.x, wid = tid >> 6, lane = tid & 63;
  int lsub = lane & 15, lrow = lane >> 4;
  float l0 = lam[0], l1 = lam[1];
  int d0 = 8 * lsub;
  float sgn = (lsub < 8) ? -1.f : 1.f;
  int jj = d0 & 63;
#pragma unroll
  for (int it = 0; it < 4; ++it) {
    int tl = wid * 16 + it * 4 + lrow;
    int t = tt * 64 + tl;
    size_t base = ((size_t)(b * T + t)) * 3072 + h * 128 + d0;
    u16x8 qraw = *(const u16x8*)(qkv + base);
    u16x8 kraw = *(const u16x8*)(qkv + base + 1024);
    u16x8 vraw = *(const u16x8*)(qkv + base + 2048);
    const float* vep = ve + ((size_t)(b * T + t)) * 1024 + h * 128 + d0;
    f32x4 ve0 = *(const f32x4*)(vep);
    f32x4 ve1 = *(const f32x4*)(vep + 4);
    float q[8], k[8];
    float sq = 0.f, sk = 0.f;
#pragma unroll
    for (int i = 0; i < 8; ++i) {
      q[i] = bf2f(qraw[i]); k[i] = bf2f(kraw[i]);
      sq += q[i] * q[i]; sk += k[i] * k[i];
    }
#pragma unroll
    for (int m = 1; m < 16; m <<= 1) {
      sq += __shfl_xor(sq, m);
      sk += __shfl_xor(sk, m);
    }
    float qs = rsqrtf(sq * (1.f / 128.f) + 1.1920929e-7f);
    float ks = rsqrtf(sk * (1.f / 128.f) + 1.1920929e-7f);
#pragma unroll
    for (int i = 0; i < 8; ++i) { q[i] *= qs; k[i] *= ks; }
    f32x4 c0 = *(const f32x4*)(ct + t * 64 + jj);
    f32x4 c1 = *(const f32x4*)(ct + t * 64 + jj + 4);
    f32x4 s0 = *(const f32x4*)(st + t * 64 + jj);
    f32x4 s1 = *(const f32x4*)(st + t * 64 + jj + 4);
    u16x8 oq, ok, ov;
#pragma unroll
    for (int i = 0; i < 8; ++i) {
      float qp = __shfl_xor(q[i], 8), kp = __shfl_xor(k[i], 8);
      float cc = (i < 4) ? c0[i & 3] : c1[i & 3];
      float ss = (i < 4) ? s0[i & 3] : s1[i & 3];
      oq[i] = f2bf(q[i] * cc + sgn * qp * ss);
      ok[i] = f2bf(k[i] * cc + sgn * kp * ss);
      float vv = (i < 4) ? ve0[i & 3] : ve1[i & 3];
      ov[i] = f2bf(l0 * bf2f(vraw[i]) + l1 * vv);
    }
    size_t orow = ((size_t)bh * T + t) * 128 + d0;
    *(u16x8*)(qn + orow) = oq;
    *(u16x8*)(kn + orow) = ok;
    *(u16x8*)&vtile[tl][d0] = ov;
  }
  __syncthreads();
#pragma unroll
  for (int it = 0; it < 4; ++it) {
    int ci = it * 256 + tid;
    int d = ci >> 3, c8 = ci & 7;
    u16x8 o;
#pragma unroll
    for (int u = 0; u < 8; u++) o[u] = vtile[c8 * 8 + u][d];
    *(u16x8*)(vt + ((size_t)bh * 128 + d) * T + tt * 64 + c8 * 8) = o;
  }
}

// ---------------- causal flash attention (4-wave, balanced pairing — best known) ------
__global__ __launch_bounds__(256, 2) void attn_kernel(
    const u16* __restrict__ Qn, const u16* __restrict__ Kn,
    const u16* __restrict__ Vt, u16* __restrict__ Y) {
  constexpr int T = 2048;
  __shared__ u16 Klds[2][64 * 128];
  __shared__ u16 Vlds[2][128 * 64];
  int bid = blockIdx.x;
  int g = bid >> 5;
  int s = (g < 8) ? (15 - g) : (g - 8);
  int bh = bid & 31;
  int b = bh >> 3, h = bh & 7;
  int tid = threadIdx.x, wid = tid >> 6, lane = tid & 63;
  int l31 = lane & 31, hh = lane >> 5;
  const u16* Qb = Qn + (size_t)bh * T * 128;
  const u16* Kb = Kn + (size_t)bh * T * 128;
  const u16* Vb = Vt + (size_t)bh * 128 * T;
  int q0w = s * 128 + wid * 32;
  int qmaxw = q0w + 31;
  int ktend = 2 * s + 2;
  int qg = q0w + l31;

  bf16x8 qf[8];
  {
    const u16* qr = Qb + (size_t)(q0w + l31) * 128 + 8 * hh;
#pragma unroll
    for (int ks = 0; ks < 8; ks++) qf[ks] = *(const bf16x8*)(qr + 16 * ks);
  }
  f32x16 acc[4];
#pragma unroll
  for (int mt = 0; mt < 4; mt++)
#pragma unroll
    for (int r = 0; r < 16; r++) acc[mt][r] = 0.f;
  float m_run = -1e30f, l_run = 0.f;

  auto stage = [&](int buf, int kt) {
#pragma unroll
    for (int it = 0; it < 4; ++it) {
      int id = wid * 256 + it * 64 + lane;
      int r = id >> 4, c = id & 15;
      gload_lds16(Kb + (size_t)(kt * 64 + r) * 128 + 8 * (c ^ (r & 7)),
                  &Klds[buf][(size_t)(wid * 256 + it * 64) * 8]);
      int rv = id >> 3, cv = id & 7;
      gload_lds16(Vb + (size_t)rv * T + kt * 64 + 8 * (cv ^ (rv & 7)),
                  &Vlds[buf][(size_t)(wid * 256 + it * 64) * 8]);
    }
  };

  stage(0, 0);

  for (int kt = 0; kt < ktend; ++kt) {
    int cur = kt & 1;
    if (kt + 1 < ktend) {
      stage(cur ^ 1, kt + 1);
      WAITVMC(8);
    } else {
      WAITVMC(0);
    }
    BAR();
    if (kt * 64 <= qmaxw) {
      const char* kb = (const char*)&Klds[cur][0];
      const char* vb = (const char*)&Vlds[cur][0];
      int rswz = (l31 & 7) << 4;
      f32x16 st0, st1;
#pragma unroll
      for (int r = 0; r < 16; r++) { st0[r] = 0.f; st1[r] = 0.f; }
      __builtin_amdgcn_s_setprio(1);
#pragma unroll
      for (int ks = 0; ks < 8; ks++) {
        bf16x8 kf0 = *(const bf16x8*)(kb + ((l31 * 256 + 32 * ks + 16 * hh) ^ rswz));
        bf16x8 kf1 = *(const bf16x8*)(kb + (((32 + l31) * 256 + 32 * ks + 16 * hh) ^ rswz));
        st0 = mfma32(kf0, qf[ks], st0);
        st1 = mfma32(kf1, qf[ks], st1);
      }
      __builtin_amdgcn_s_setprio(0);
      bool edge = (kt == (qmaxw >> 6));
      if (edge) {
#pragma unroll
        for (int r = 0; r < 16; r++) {
          int kvb = kt * 64 + (r & 3) + 8 * (r >> 2) + 4 * hh;
          if (kvb > qg) st0[r] = -1e30f;
          if (kvb + 32 > qg) st1[r] = -1e30f;
        }
      }
      float m8[8];
#pragma unroll
      for (int r = 0; r < 8; r++)
        m8[r] = fmaxf(fmaxf(st0[r], st0[r + 8]), fmaxf(st1[r], st1[r + 8]));
#pragma unroll
      for (int r = 0; r < 4; r++) m8[r] = fmaxf(m8[r], m8[r + 4]);
      float pm = fmaxf(fmaxf(m8[0], m8[1]), fmaxf(m8[2], m8[3]));
      pm = fmaxf(pm, __shfl_xor(pm, 32));
      float pmn = pm * SCALE_W;
      bool nos = __all(pmn <= m_run + DEFER_THR);
      float mnew = nos ? m_run : fmaxf(m_run, pmn);
      if (!nos) {
        float alpha = EXPW(m_run - mnew);
        l_run *= alpha;
#pragma unroll
        for (int mt = 0; mt < 4; mt++)
#pragma unroll
          for (int r = 0; r < 16; r++) acc[mt][r] *= alpha;
        m_run = mnew;
      }
      float sa = 0.f, sb = 0.f, sc = 0.f, sd = 0.f;
#pragma unroll
      for (int r = 0; r < 4; r++) {
        st0[r]      = EXPW(fmaf(st0[r],      SCALE_W, -mnew)); sa += st0[r];
        st0[r + 4]  = EXPW(fmaf(st0[r + 4],  SCALE_W, -mnew)); sb += st0[r + 4];
        st0[r + 8]  = EXPW(fmaf(st0[r + 8],  SCALE_W, -mnew)); sc += st0[r + 8];
        st0[r + 12] = EXPW(fmaf(st0[r + 12], SCALE_W, -mnew)); sd += st0[r + 12];
        st1[r]      = EXPW(fmaf(st1[r],      SCALE_W, -mnew)); sa += st1[r];
        st1[r + 4]  = EXPW(fmaf(st1[r + 4],  SCALE_W, -mnew)); sb += st1[r + 4];
        st1[r + 8]  = EXPW(fmaf(st1[r + 8],  SCALE_W, -mnew)); sc += st1[r + 8];
        st1[r + 12] = EXPW(fmaf(st1[r + 12], SCALE_W, -mnew)); sd += st1[r + 12];
      }
      float ps = (sa + sb) + (sc + sd);
      ps += __shfl_xor(ps, 32);
      l_run += ps;
      unsigned pA0[4], pB0[4], pA1[4], pB1[4];
#pragma unroll
      for (int rr = 0; rr < 4; rr++) {
        pA0[rr] = cvtpk_bf16(st0[4 * rr], st0[4 * rr + 1]);
        pB0[rr] = cvtpk_bf16(st0[4 * rr + 2], st0[4 * rr + 3]);
        pA1[rr] = cvtpk_bf16(st1[4 * rr], st1[4 * rr + 1]);
        pB1[rr] = cvtpk_bf16(st1[4 * rr + 2], st1[4 * rr + 3]);
      }
      bf16x8 pf[4];
#pragma unroll
      for (int ks2 = 0; ks2 < 4; ks2++) {
        int k1 = ks2 & 1;
        unsigned a0, b0, a1, b1;
        if (ks2 < 2) { a0 = pA0[2 * k1]; b0 = pA0[2 * k1 + 1]; a1 = pB0[2 * k1]; b1 = pB0[2 * k1 + 1]; }
        else         { a0 = pA1[2 * k1]; b0 = pA1[2 * k1 + 1]; a1 = pB1[2 * k1]; b1 = pB1[2 * k1 + 1]; }
        pswap32(a0, b0);
        pswap32(a1, b1);
        union { unsigned w[4]; bf16x8 v; } u;
        u.w[0] = a0; u.w[1] = a1; u.w[2] = b0; u.w[3] = b1;
        pf[ks2] = u.v;
      }
      __builtin_amdgcn_s_setprio(1);
#pragma unroll
      for (int mt = 0; mt < 4; mt++) {
        int row = 32 * mt + l31;
#pragma unroll
        for (int ks2 = 0; ks2 < 4; ks2++) {
          bf16x8 vf = *(const bf16x8*)(vb + ((row * 128 + 32 * ks2 + 16 * hh) ^ rswz));
          acc[mt] = mfma32(vf, pf[ks2], acc[mt]);
        }
      }
      __builtin_amdgcn_s_setprio(0);
    }
    BAR();
  }
  float linv = 1.f / l_run;
  size_t yrow = (size_t)b * T + q0w + l31;
  u16* yp = Y + yrow * 1024 + h * 128;
#pragma unroll
  for (int mt = 0; mt < 4; mt++) {
#pragma unroll
    for (int rr = 0; rr < 4; rr++) {
      u16x4 o;
#pragma unroll
      for (int i = 0; i < 4; i++) o[i] = f2bf(acc[mt][4 * rr + i] * linv);
      *(u16x4*)(yp + 32 * mt + 8 * rr + 4 * hh) = o;
    }
  }
}

// ---------------- launch ----------------
extern "C" void kernel_launch(void* const* d_in, const int* in_sizes, int n_in,
                              void* d_out, int out_size, void* d_ws, size_t ws_size,
                              hipStream_t stream) {
  (void)in_sizes; (void)n_in; (void)out_size; (void)ws_size;
  const float* x = (const float*)d_in[0];
  const float* ve = (const float*)d_in[1];
  const float* qkvw = (const float*)d_in[2];
  const float* lam = (const float*)d_in[3];
  const float* cpw = (const float*)d_in[4];
  const float* cpb = (const float*)d_in[5];
  float* out = (float*)d_out;
  char* ws = (char*)d_ws;

  u16* xb   = (u16*)(ws + 0);           // 16 MB  (aliased by y after GEMM1)
  u16* wqkv = (u16*)(ws + 16777216);    // 6 MB
  u16* wp   = (u16*)(ws + 23068672);    // 2 MB
  u16* qkv  = (u16*)(ws + 25165824);    // 48 MB
  u16* qn   = (u16*)(ws + 75497472);    // 16 MB
  u16* kn   = (u16*)(ws + 92274688);    // 16 MB
  u16* vt   = (u16*)(ws + 109051904);   // 16 MB
  float* ctab = (float*)(ws + 125829120);  // 0.5 MB
  float* stab = (float*)(ws + 126353408);  // 0.5 MB
  u16* y = xb;                          // alias: xb dead after GEMM1

  init_kernel<<<12800, 256, 0, stream>>>(x, qkvw, cpw, xb, wqkv, wp, ctab, stab);
  gemm192_kernel<<<512, 512, 0, stream>>>(xb, wqkv, qkv, 8192, 3072, 1024, 16);
  transform_kernel<<<dim3(32, 32), 256, 0, stream>>>(qkv, ve, lam, ctab, stab, qn, kn, vt);
  attn_kernel<<<512, 256, 0, stream>>>(qn, kn, vt, y);
  gemm4p_kernel<64, 1><<<512, 512, 0, stream>>>(y, wp, out, cpb, 8192, 1024, 1024, 4);
}

// Round 17
// 184.840 us; speedup vs baseline: 1.1135x; 1.0042x over previous
//
#include <hip/hip_runtime.h>
#include <math.h>

typedef unsigned short u16;
typedef short bf16x8 __attribute__((ext_vector_type(8)));
typedef u16 u16x2 __attribute__((ext_vector_type(2)));
typedef u16 u16x4 __attribute__((ext_vector_type(4)));
typedef u16 u16x8 __attribute__((ext_vector_type(8)));
typedef float f32x2 __attribute__((ext_vector_type(2)));
typedef float f32x4 __attribute__((ext_vector_type(4)));
typedef float f32x16 __attribute__((ext_vector_type(16)));

typedef __attribute__((address_space(1))) const void gvoid_t;
typedef __attribute__((address_space(3))) void lvoid_t;

__device__ __forceinline__ u16 f2bf(float f) {
  union { float f; unsigned u; } v; v.f = f;
  unsigned r = v.u + 0x7fffu + ((v.u >> 16) & 1u);
  return (u16)(r >> 16);
}
__device__ __forceinline__ float bf2f(u16 h) {
  union { unsigned u; float f; } v; v.u = ((unsigned)h) << 16;
  return v.f;
}
__device__ __forceinline__ f32x4 mfma16(bf16x8 a, bf16x8 b, f32x4 c) {
  return __builtin_amdgcn_mfma_f32_16x16x32_bf16(a, b, c, 0, 0, 0);
}
__device__ __forceinline__ f32x16 mfma32(bf16x8 a, bf16x8 b, f32x16 c) {
  return __builtin_amdgcn_mfma_f32_32x32x16_bf16(a, b, c, 0, 0, 0);
}
__device__ __forceinline__ void gload_lds16(const void* g, void* l) {
  __builtin_amdgcn_global_load_lds((gvoid_t*)g, (lvoid_t*)l, 16, 0, 0);
}
__device__ __forceinline__ unsigned cvtpk_bf16(float lo, float hi) {
  unsigned r;
  asm("v_cvt_pk_bf16_f32 %0, %1, %2" : "=v"(r) : "v"(lo), "v"(hi));
  return r;
}
__device__ __forceinline__ void pswap32(unsigned& a, unsigned& b) {
  asm("v_permlane32_swap_b32 %0, %1" : "+v"(a), "+v"(b));
}

#if __has_builtin(__builtin_amdgcn_exp2f)
#define EXPW(x) __builtin_amdgcn_exp2f(x)
#define SCALE_W 0.17312354f     /* 0.12 * log2(e) */
#define DEFER_THR 11.5415603f   /* 8 * log2(e) */
#else
#define EXPW(x) __expf(x)
#define SCALE_W 0.12f
#define DEFER_THR 8.0f
#endif

#define BAR() __builtin_amdgcn_s_barrier()
#define WAITLGKM()                          \
  asm volatile("s_waitcnt lgkmcnt(0)");     \
  __builtin_amdgcn_sched_barrier(0)
#define WAITVMC(N)                                    \
  do {                                                \
    __builtin_amdgcn_s_waitcnt(0x0F70 | (N));         \
    __builtin_amdgcn_sched_barrier(0);                \
  } while (0)

// ---------------- fused init: fp32->bf16 for x/qkvw/cpw + RoPE tables ----------------
__global__ __launch_bounds__(256) void init_kernel(
    const float* __restrict__ x, const float* __restrict__ qkvw,
    const float* __restrict__ cpw, u16* __restrict__ xb, u16* __restrict__ wqkv,
    u16* __restrict__ wp, float* __restrict__ ct, float* __restrict__ st) {
  int blk = blockIdx.x;
  if (blk < 12288) {
    int i = blk * 256 + threadIdx.x;
    const float* src;
    u16* dst;
    int off;
    if (i < 2097152) { src = x; dst = xb; off = i; }
    else if (i < 2883584) { src = qkvw; dst = wqkv; off = i - 2097152; }
    else { src = cpw; dst = wp; off = i - 2883584; }
    f32x4 v = *(const f32x4*)(src + (size_t)off * 4);
    u16x4 o;
    o[0] = f2bf(v[0]); o[1] = f2bf(v[1]); o[2] = f2bf(v[2]); o[3] = f2bf(v[3]);
    *(u16x4*)(dst + (size_t)off * 4) = o;
  } else {
    int i = (blk - 12288) * 256 + threadIdx.x;
    int t = i >> 6, j = i & 63;
    float inv = powf(10000.f, -(float)j * (1.0f / 64.0f));
    float ang = (float)t * inv;
    ct[i] = cosf(ang);
    st[i] = sinf(ang);
  }
}

// ---------------- 256x192 2-phase GEMM (empirically best; GEMM1) ----------
__global__ __launch_bounds__(512, 1) void gemm192_kernel(
    const u16* __restrict__ A, const u16* __restrict__ B, u16* __restrict__ C,
    int M, int N, int K, int nbn) {
  constexpr int WM = 128;
  constexpr int MI = 4;
  constexpr int NI = 3;
  constexpr int AR = 4;
  constexpr int NR = 7;
  __shared__ u16 Alds[2][256 * 64];
  __shared__ u16 Blds[2][192 * 64];
  int nwg = gridDim.x;
  int cpx = nwg >> 3;
  int bid = blockIdx.x;
  int swz = (bid & 7) * cpx + (bid >> 3);
  int bm = (swz & 3) + 4 * (swz / (4 * nbn));
  int bn = (swz >> 2) % nbn;
  size_t m0 = (size_t)bm * 256, n0 = (size_t)bn * 192;
  int tid = threadIdx.x, wid = tid >> 6, lane = tid & 63;
  int wr = wid >> 2, wc = wid & 3, l15 = lane & 15, l4 = lane >> 4;
  int srow = tid >> 3, sch = tid & 7;

  const u16* Abase = A + m0 * K;
  const u16* Bbase = B + n0 * K;

  f32x4 acc[8][NI];
#pragma unroll
  for (int m = 0; m < 8; m++)
#pragma unroll
    for (int n = 0; n < NI; n++) acc[m][n] = f32x4{0.f, 0.f, 0.f, 0.f};

  auto stageR = [&](int buf, int kt, int r) {
    if (r < AR) {
      int row = 64 * r + srow;
      gload_lds16(Abase + (size_t)row * K + kt * 64 + 8 * (sch ^ (row & 7)),
                  &Alds[buf][(64 * r + 8 * wid) * 64]);
    } else {
      int row = 64 * (r - AR) + srow;
      gload_lds16(Bbase + (size_t)row * K + kt * 64 + 8 * (sch ^ (row & 7)),
                  &Blds[buf][(64 * (r - AR) + 8 * wid) * 64]);
    }
  };
  auto rdA = [&](int buf, int half, bf16x8 (&a)[MI][2]) {
#pragma unroll
    for (int mi = 0; mi < MI; ++mi)
#pragma unroll
      for (int kk = 0; kk < 2; ++kk) {
        int row = WM * wr + 64 * half + 16 * mi + l15;
        a[mi][kk] = *(const bf16x8*)((const char*)(&Alds[buf][0]) + row * 128 +
                                     ((kk * 64 + 16 * l4) ^ ((row & 7) << 4)));
      }
  };
  auto rdB = [&](int buf, bf16x8 (&bb)[NI][2]) {
#pragma unroll
    for (int ni = 0; ni < NI; ++ni)
#pragma unroll
      for (int kk = 0; kk < 2; ++kk) {
        int row = 48 * wc + 16 * ni + l15;
        bb[ni][kk] = *(const bf16x8*)((const char*)(&Blds[buf][0]) + row * 128 +
                                      ((kk * 64 + 16 * l4) ^ ((row & 7) << 4)));
      }
  };

#define HALFM(AF, BF, QM)                                                 \
  do {                                                                    \
    __builtin_amdgcn_s_setprio(1);                                        \
    _Pragma("unroll") for (int mi = 0; mi < MI; ++mi)                     \
        _Pragma("unroll") for (int ni = 0; ni < NI; ++ni)                 \
            _Pragma("unroll") for (int kk = 0; kk < 2; ++kk)              \
                acc[4 * QM + mi][ni] =                                    \
        mfma16(AF[mi][kk], BF[ni][kk], acc[4 * QM + mi][ni]);             \
    __builtin_amdgcn_s_setprio(0);                                        \
  } while (0)

#pragma unroll
  for (int r = 0; r < NR; ++r) stageR(0, 0, r);
  WAITVMC(0);
  BAR();

  int nk = K >> 6;
  bf16x8 a[MI][2], b[NI][2];
  for (int t = 0; t < nk; ++t) {
    int buf = t & 1, nxt = buf ^ 1;
    bool pf = (t + 1 < nk);
    rdA(buf, 0, a);
    rdB(buf, b);
    if (pf) { stageR(nxt, t + 1, 0); stageR(nxt, t + 1, 1); stageR(nxt, t + 1, 2); stageR(nxt, t + 1, 3); }
    BAR();
    WAITLGKM();
    HALFM(a, b, 0);
    BAR();
    rdA(buf, 1, a);
    if (pf) { stageR(nxt, t + 1, 4); stageR(nxt, t + 1, 5); stageR(nxt, t + 1, 6); }
    BAR();
    WAITLGKM();
    HALFM(a, b, 1);
    WAITVMC(0);
    BAR();
  }

#pragma unroll
  for (int mi = 0; mi < 8; ++mi) {
#pragma unroll
    for (int ni = 0; ni < NI; ++ni) {
      size_t row = m0 + WM * wr + 16 * mi + 4 * l4;
      size_t col = n0 + 48 * wc + 16 * ni + l15;
#pragma unroll
      for (int i = 0; i < 4; ++i) {
        C[(row + i) * N + col] = f2bf(acc[mi][ni][i]);
      }
    }
  }
#undef HALFM
}

// ---------------- BM=64 4-phase GEMM (GEMM2) — all staging issued at ph0 ------
template <int BM, int OUTF32>
__global__ __launch_bounds__(512, 1) void gemm4p_kernel(
    const u16* __restrict__ A, const u16* __restrict__ B, void* __restrict__ C,
    const float* __restrict__ bias, int M, int N, int K, int nbn) {
  constexpr int WM = BM / 2;
  constexpr int MI = (WM / 32 > 0) ? WM / 32 : 1;
  constexpr int NACC = 2 * MI;
  constexpr int AR = BM / 64;
  constexpr int NR = AR + 4;
  __shared__ u16 Alds[2][BM * 64];
  __shared__ u16 Blds[2][256 * 64];
  int nwg = gridDim.x;
  int cpx = nwg >> 3;
  int bid = blockIdx.x;
  int swz = (bid & 7) * cpx + (bid >> 3);
  int bm = (swz & 3) + 4 * (swz / (4 * nbn));
  int bn = (swz >> 2) % nbn;
  size_t m0 = (size_t)bm * BM, n0 = (size_t)bn * 256;
  int tid = threadIdx.x, wid = tid >> 6, lane = tid & 63;
  int wr = wid >> 2, wc = wid & 3, l15 = lane & 15, l4 = lane >> 4;
  int srow = tid >> 3, sch = tid & 7;

  const u16* Abase = A + m0 * K;
  const u16* Bbase = B + n0 * K;

  f32x4 acc[NACC][4];
#pragma unroll
  for (int m = 0; m < NACC; m++)
#pragma unroll
    for (int n = 0; n < 4; n++) acc[m][n] = f32x4{0.f, 0.f, 0.f, 0.f};

  auto stageR = [&](int buf, int kt, int r) {
    if (r < AR) {
      int row = 64 * r + srow;
      gload_lds16(Abase + (size_t)row * K + kt * 64 + 8 * (sch ^ (row & 7)),
                  &Alds[buf][(64 * r + 8 * wid) * 64]);
    } else {
      int row = 64 * (r - AR) + srow;
      gload_lds16(Bbase + (size_t)row * K + kt * 64 + 8 * (sch ^ (row & 7)),
                  &Blds[buf][(64 * (r - AR) + 8 * wid) * 64]);
    }
  };
  auto rdA = [&](int buf, int qm, bf16x8 (&a)[MI][2]) {
#pragma unroll
    for (int mi = 0; mi < MI; ++mi)
#pragma unroll
      for (int kk = 0; kk < 2; ++kk) {
        int row = WM * wr + (WM / 2) * qm + 16 * mi + l15;
        a[mi][kk] = *(const bf16x8*)((const char*)(&Alds[buf][0]) + row * 128 +
                                     ((kk * 64 + 16 * l4) ^ ((row & 7) << 4)));
      }
  };
  auto rdB = [&](int buf, int qn, bf16x8 (&bb)[2][2]) {
#pragma unroll
    for (int ni = 0; ni < 2; ++ni)
#pragma unroll
      for (int kk = 0; kk < 2; ++kk) {
        int row = 64 * wc + 32 * qn + 16 * ni + l15;
        bb[ni][kk] = *(const bf16x8*)((const char*)(&Blds[buf][0]) + row * 128 +
                                      ((kk * 64 + 16 * l4) ^ ((row & 7) << 4)));
      }
  };

#define QUADX(AF, BF, QM, QN)                                             \
  do {                                                                    \
    __builtin_amdgcn_s_setprio(1);                                        \
    _Pragma("unroll") for (int mi = 0; mi < MI; ++mi)                     \
        _Pragma("unroll") for (int ni = 0; ni < 2; ++ni)                  \
            _Pragma("unroll") for (int kk = 0; kk < 2; ++kk)              \
                acc[MI * QM + mi][2 * QN + ni] =                          \
        mfma16(AF[mi][kk], BF[ni][kk], acc[MI * QM + mi][2 * QN + ni]);   \
    __builtin_amdgcn_s_setprio(0);                                        \
  } while (0)

#pragma unroll
  for (int r = 0; r < NR; ++r) stageR(0, 0, r);
  WAITVMC(0);
  BAR();

  int nk = K >> 6;
  bf16x8 a[MI][2], b0[2][2], b1[2][2];
  for (int t = 0; t < nk; ++t) {
    int buf = t & 1, nxt = buf ^ 1;
    bool pf = (t + 1 < nk);
    rdA(buf, 0, a);
    rdB(buf, 0, b0);
    if (pf) {
#pragma unroll
      for (int r = 0; r < NR; ++r) stageR(nxt, t + 1, r);
    }
    BAR();
    WAITLGKM();
    QUADX(a, b0, 0, 0);
    BAR();
    rdB(buf, 1, b1);
    BAR();
    WAITLGKM();
    QUADX(a, b1, 0, 1);
    BAR();
    rdA(buf, 1, a);
    BAR();
    WAITLGKM();
    QUADX(a, b0, 1, 0);
    BAR();
    QUADX(a, b1, 1, 1);
    WAITVMC(0);
    BAR();
  }

#pragma unroll
  for (int mi = 0; mi < NACC; ++mi) {
#pragma unroll
    for (int ni = 0; ni < 4; ++ni) {
      size_t row = m0 + WM * wr + 16 * mi + 4 * l4;
      size_t col = n0 + 64 * wc + 16 * ni + l15;
#pragma unroll
      for (int i = 0; i < 4; ++i) {
        float v = acc[mi][ni][i];
        if constexpr (OUTF32) {
          ((float*)C)[(row + i) * N + col] = v + bias[col];
        } else {
          ((u16*)C)[(row + i) * N + col] = f2bf(v);
        }
      }
    }
  }
#undef QUADX
}

// ---------------- transform: RMSNorm + RoPE + v-mix ----------------
__global__ __launch_bounds__(256) void transform_kernel(
    const u16* __restrict__ qkv, const float* __restrict__ ve,
    const float* __restrict__ lam, const float* __restrict__ ct,
    const float* __restrict__ st, u16* __restrict__ qn, u16* __restrict__ kn,
    u16* __restrict__ vt) {
  constexpr int T = 2048;
  __shared__ u16 vtile[64][136];
  int tt = blockIdx.x, bh = blockIdx.y;
  int b = bh >> 3, h = bh & 7;
  int tid = threadIdx.x, wid = tid >> 6, lane = tid & 63;
  int lsub = lane & 15, lrow = lane >> 4;
  float l0 = lam[0], l1 = lam[1];
  int d0 = 8 * lsub;
  float sgn = (lsub < 8) ? -1.f : 1.f;
  int jj = d0 & 63;
#pragma unroll
  for (int it = 0; it < 4; ++it) {
    int tl = wid * 16 + it * 4 + lrow;
    int t = tt * 64 + tl;
    size_t base = ((size_t)(b * T + t)) * 3072 + h * 128 + d0;
    u16x8 qraw = *(const u16x8*)(qkv + base);
    u16x8 kraw = *(const u16x8*)(qkv + base + 1024);
    u16x8 vraw = *(const u16x8*)(qkv + base + 2048);
    const float* vep = ve + ((size_t)(b * T + t)) * 1024 + h * 128 + d0;
    f32x4 ve0 = *(const f32x4*)(vep);
    f32x4 ve1 = *(const f32x4*)(vep + 4);
    float q[8], k[8];
    float sq = 0.f, sk = 0.f;
#pragma unroll
    for (int i = 0; i < 8; ++i) {
      q[i] = bf2f(qraw[i]); k[i] = bf2f(kraw[i]);
      sq += q[i] * q[i]; sk += k[i] * k[i];
    }
#pragma unroll
    for (int m = 1; m < 16; m <<= 1) {
      sq += __shfl_xor(sq, m);
      sk += __shfl_xor(sk, m);
    }
    float qs = rsqrtf(sq * (1.f / 128.f) + 1.1920929e-7f);
    float ks = rsqrtf(sk * (1.f / 128.f) + 1.1920929e-7f);
#pragma unroll
    for (int i = 0; i < 8; ++i) { q[i] *= qs; k[i] *= ks; }
    f32x4 c0 = *(const f32x4*)(ct + t * 64 + jj);
    f32x4 c1 = *(const f32x4*)(ct + t * 64 + jj + 4);
    f32x4 s0 = *(const f32x4*)(st + t * 64 + jj);
    f32x4 s1 = *(const f32x4*)(st + t * 64 + jj + 4);
    u16x8 oq, ok, ov;
#pragma unroll
    for (int i = 0; i < 8; ++i) {
      float qp = __shfl_xor(q[i], 8), kp = __shfl_xor(k[i], 8);
      float cc = (i < 4) ? c0[i & 3] : c1[i & 3];
      float ss = (i < 4) ? s0[i & 3] : s1[i & 3];
      oq[i] = f2bf(q[i] * cc + sgn * qp * ss);
      ok[i] = f2bf(k[i] * cc + sgn * kp * ss);
      float vv = (i < 4) ? ve0[i & 3] : ve1[i & 3];
      ov[i] = f2bf(l0 * bf2f(vraw[i]) + l1 * vv);
    }
    size_t orow = ((size_t)bh * T + t) * 128 + d0;
    *(u16x8*)(qn + orow) = oq;
    *(u16x8*)(kn + orow) = ok;
    *(u16x8*)&vtile[tl][d0] = ov;
  }
  __syncthreads();
#pragma unroll
  for (int it = 0; it < 4; ++it) {
    int ci = it * 256 + tid;
    int d = ci >> 3, c8 = ci & 7;
    u16x8 o;
#pragma unroll
    for (int u = 0; u < 8; u++) o[u] = vtile[c8 * 8 + u][d];
    *(u16x8*)(vt + ((size_t)bh * 128 + d) * T + tt * 64 + c8 * 8) = o;
  }
}

// ---------------- causal flash attention (4-wave, balanced pairing — best known) ------
__global__ __launch_bounds__(256, 2) void attn_kernel(
    const u16* __restrict__ Qn, const u16* __restrict__ Kn,
    const u16* __restrict__ Vt, u16* __restrict__ Y) {
  constexpr int T = 2048;
  __shared__ u16 Klds[2][64 * 128];
  __shared__ u16 Vlds[2][128 * 64];
  int bid = blockIdx.x;
  int g = bid >> 5;
  int s = (g < 8) ? (15 - g) : (g - 8);
  int bh = bid & 31;
  int b = bh >> 3, h = bh & 7;
  int tid = threadIdx.x, wid = tid >> 6, lane = tid & 63;
  int l31 = lane & 31, hh = lane >> 5;
  const u16* Qb = Qn + (size_t)bh * T * 128;
  const u16* Kb = Kn + (size_t)bh * T * 128;
  const u16* Vb = Vt + (size_t)bh * 128 * T;
  int q0w = s * 128 + wid * 32;
  int qmaxw = q0w + 31;
  int ktend = 2 * s + 2;
  int qg = q0w + l31;

  bf16x8 qf[8];
  {
    const u16* qr = Qb + (size_t)(q0w + l31) * 128 + 8 * hh;
#pragma unroll
    for (int ks = 0; ks < 8; ks++) qf[ks] = *(const bf16x8*)(qr + 16 * ks);
  }
  f32x16 acc[4];
#pragma unroll
  for (int mt = 0; mt < 4; mt++)
#pragma unroll
    for (int r = 0; r < 16; r++) acc[mt][r] = 0.f;
  float m_run = -1e30f, l_run = 0.f;

  auto stage = [&](int buf, int kt) {
#pragma unroll
    for (int it = 0; it < 4; ++it) {
      int id = wid * 256 + it * 64 + lane;
      int r = id >> 4, c = id & 15;
      gload_lds16(Kb + (size_t)(kt * 64 + r) * 128 + 8 * (c ^ (r & 7)),
                  &Klds[buf][(size_t)(wid * 256 + it * 64) * 8]);
      int rv = id >> 3, cv = id & 7;
      gload_lds16(Vb + (size_t)rv * T + kt * 64 + 8 * (cv ^ (rv & 7)),
                  &Vlds[buf][(size_t)(wid * 256 + it * 64) * 8]);
    }
  };

  stage(0, 0);

  for (int kt = 0; kt < ktend; ++kt) {
    int cur = kt & 1;
    if (kt + 1 < ktend) {
      stage(cur ^ 1, kt + 1);
      WAITVMC(8);
    } else {
      WAITVMC(0);
    }
    BAR();
    if (kt * 64 <= qmaxw) {
      const char* kb = (const char*)&Klds[cur][0];
      const char* vb = (const char*)&Vlds[cur][0];
      int rswz = (l31 & 7) << 4;
      f32x16 st0, st1;
#pragma unroll
      for (int r = 0; r < 16; r++) { st0[r] = 0.f; st1[r] = 0.f; }
      __builtin_amdgcn_s_setprio(1);
#pragma unroll
      for (int ks = 0; ks < 8; ks++) {
        bf16x8 kf0 = *(const bf16x8*)(kb + ((l31 * 256 + 32 * ks + 16 * hh) ^ rswz));
        bf16x8 kf1 = *(const bf16x8*)(kb + (((32 + l31) * 256 + 32 * ks + 16 * hh) ^ rswz));
        st0 = mfma32(kf0, qf[ks], st0);
        st1 = mfma32(kf1, qf[ks], st1);
      }
      __builtin_amdgcn_s_setprio(0);
      bool edge = (kt == (qmaxw >> 6));
      if (edge) {
#pragma unroll
        for (int r = 0; r < 16; r++) {
          int kvb = kt * 64 + (r & 3) + 8 * (r >> 2) + 4 * hh;
          if (kvb > qg) st0[r] = -1e30f;
          if (kvb + 32 > qg) st1[r] = -1e30f;
        }
      }
      float m8[8];
#pragma unroll
      for (int r = 0; r < 8; r++)
        m8[r] = fmaxf(fmaxf(st0[r], st0[r + 8]), fmaxf(st1[r], st1[r + 8]));
#pragma unroll
      for (int r = 0; r < 4; r++) m8[r] = fmaxf(m8[r], m8[r + 4]);
      float pm = fmaxf(fmaxf(m8[0], m8[1]), fmaxf(m8[2], m8[3]));
      pm = fmaxf(pm, __shfl_xor(pm, 32));
      float pmn = pm * SCALE_W;
      bool nos = __all(pmn <= m_run + DEFER_THR);
      float mnew = nos ? m_run : fmaxf(m_run, pmn);
      if (!nos) {
        float alpha = EXPW(m_run - mnew);
        l_run *= alpha;
#pragma unroll
        for (int mt = 0; mt < 4; mt++)
#pragma unroll
          for (int r = 0; r < 16; r++) acc[mt][r] *= alpha;
        m_run = mnew;
      }
      float sa = 0.f, sb = 0.f, sc = 0.f, sd = 0.f;
#pragma unroll
      for (int r = 0; r < 4; r++) {
        st0[r]      = EXPW(fmaf(st0[r],      SCALE_W, -mnew)); sa += st0[r];
        st0[r + 4]  = EXPW(fmaf(st0[r + 4],  SCALE_W, -mnew)); sb += st0[r + 4];
        st0[r + 8]  = EXPW(fmaf(st0[r + 8],  SCALE_W, -mnew)); sc += st0[r + 8];
        st0[r + 12] = EXPW(fmaf(st0[r + 12], SCALE_W, -mnew)); sd += st0[r + 12];
        st1[r]      = EXPW(fmaf(st1[r],      SCALE_W, -mnew)); sa += st1[r];
        st1[r + 4]  = EXPW(fmaf(st1[r + 4],  SCALE_W, -mnew)); sb += st1[r + 4];
        st1[r + 8]  = EXPW(fmaf(st1[r + 8],  SCALE_W, -mnew)); sc += st1[r + 8];
        st1[r + 12] = EXPW(fmaf(st1[r + 12], SCALE_W, -mnew)); sd += st1[r + 12];
      }
      float ps = (sa + sb) + (sc + sd);
      ps += __shfl_xor(ps, 32);
      l_run += ps;
      unsigned pA0[4], pB0[4], pA1[4], pB1[4];
#pragma unroll
      for (int rr = 0; rr < 4; rr++) {
        pA0[rr] = cvtpk_bf16(st0[4 * rr], st0[4 * rr + 1]);
        pB0[rr] = cvtpk_bf16(st0[4 * rr + 2], st0[4 * rr + 3]);
        pA1[rr] = cvtpk_bf16(st1[4 * rr], st1[4 * rr + 1]);
        pB1[rr] = cvtpk_bf16(st1[4 * rr + 2], st1[4 * rr + 3]);
      }
      bf16x8 pf[4];
#pragma unroll
      for (int ks2 = 0; ks2 < 4; ks2++) {
        int k1 = ks2 & 1;
        unsigned a0, b0, a1, b1;
        if (ks2 < 2) { a0 = pA0[2 * k1]; b0 = pA0[2 * k1 + 1]; a1 = pB0[2 * k1]; b1 = pB0[2 * k1 + 1]; }
        else         { a0 = pA1[2 * k1]; b0 = pA1[2 * k1 + 1]; a1 = pB1[2 * k1]; b1 = pB1[2 * k1 + 1]; }
        pswap32(a0, b0);
        pswap32(a1, b1);
        union { unsigned w[4]; bf16x8 v; } u;
        u.w[0] = a0; u.w[1] = a1; u.w[2] = b0; u.w[3] = b1;
        pf[ks2] = u.v;
      }
      __builtin_amdgcn_s_setprio(1);
#pragma unroll
      for (int mt = 0; mt < 4; mt++) {
        int row = 32 * mt + l31;
#pragma unroll
        for (int ks2 = 0; ks2 < 4; ks2++) {
          bf16x8 vf = *(const bf16x8*)(vb + ((row * 128 + 32 * ks2 + 16 * hh) ^ rswz));
          acc[mt] = mfma32(vf, pf[ks2], acc[mt]);
        }
      }
      __builtin_amdgcn_s_setprio(0);
    }
    BAR();
  }
  float linv = 1.f / l_run;
  size_t yrow = (size_t)b * T + q0w + l31;
  u16* yp = Y + yrow * 1024 + h * 128;
#pragma unroll
  for (int mt = 0; mt < 4; mt++) {
#pragma unroll
    for (int rr = 0; rr < 4; rr++) {
      u16x4 o;
#pragma unroll
      for (int i = 0; i < 4; i++) o[i] = f2bf(acc[mt][4 * rr + i] * linv);
      *(u16x4*)(yp + 32 * mt + 8 * rr + 4 * hh) = o;
    }
  }
}

// ---------------- launch ----------------
extern "C" void kernel_launch(void* const* d_in, const int* in_sizes, int n_in,
                              void* d_out, int out_size, void* d_ws, size_t ws_size,
                              hipStream_t stream) {
  (void)in_sizes; (void)n_in; (void)out_size; (void)ws_size;
  const float* x = (const float*)d_in[0];
  const float* ve = (const float*)d_in[1];
  const float* qkvw = (const float*)d_in[2];
  const float* lam = (const float*)d_in[3];
  const float* cpw = (const float*)d_in[4];
  const float* cpb = (const float*)d_in[5];
  float* out = (float*)d_out;
  char* ws = (char*)d_ws;

  u16* xb   = (u16*)(ws + 0);           // 16 MB  (aliased by y after GEMM1)
  u16* wqkv = (u16*)(ws + 16777216);    // 6 MB
  u16* wp   = (u16*)(ws + 23068672);    // 2 MB
  u16* qkv  = (u16*)(ws + 25165824);    // 48 MB
  u16* qn   = (u16*)(ws + 75497472);    // 16 MB
  u16* kn   = (u16*)(ws + 92274688);    // 16 MB
  u16* vt   = (u16*)(ws + 109051904);   // 16 MB
  float* ctab = (float*)(ws + 125829120);  // 0.5 MB
  float* stab = (float*)(ws + 126353408);  // 0.5 MB
  u16* y = xb;                          // alias: xb dead after GEMM1

  init_kernel<<<12800, 256, 0, stream>>>(x, qkvw, cpw, xb, wqkv, wp, ctab, stab);
  gemm192_kernel<<<512, 512, 0, stream>>>(xb, wqkv, qkv, 8192, 3072, 1024, 16);
  transform_kernel<<<dim3(32, 32), 256, 0, stream>>>(qkv, ve, lam, ctab, stab, qn, kn, vt);
  attn_kernel<<<512, 256, 0, stream>>>(qn, kn, vt, y);
  gemm4p_kernel<64, 1><<<512, 512, 0, stream>>>(y, wp, out, cpb, 8192, 1024, 1024, 4);
}